// Round 1
// baseline (154.500 us; speedup 1.0000x reference)
//
#include <hip/hip_runtime.h>

// Problem constants: B=8, N=256, D=128, 2D=256
// Outputs: improved_tour [8,256] (=arange), improvement_matrix [8,256,256]
// d_out = 2048 + 524288 = 526336 floats, tour first.

typedef __attribute__((ext_vector_type(8))) short short8;
typedef __attribute__((ext_vector_type(4))) float floatx4;

static __device__ __forceinline__ unsigned short f2bf(float f) {
  // round-to-nearest-even fp32 -> bf16 (finite values only here)
  unsigned int x = __float_as_uint(f);
  x += 0x7fff + ((x >> 16) & 1);
  return (unsigned short)(x >> 16);
}

// ---------------- prep: tour output, zero matrix, W2 -> bf16 transposed ----
__global__ __launch_bounds__(256) void k_prep(const float* __restrict__ W2,
                                              float* __restrict__ out,
                                              unsigned short* __restrict__ W2T) {
  int e = blockIdx.x * 256 + threadIdx.x;  // grid covers 559104
  if (e < 2048) {
    out[e] = (float)(e & 255);             // improved_tour rows = arange(256)
  } else if (e < 526336) {
    out[e] = 0.f;                          // masked entries must be 0
  } else {
    int e2 = e - 526336;                   // 32768 W2 elements, [256k][128n]
    int k = e2 >> 7, n = e2 & 127;
    W2T[n * 256 + k] = f2bf(W2[e2]);       // W2T[n][k] bf16
  }
}

// ---------------- proj: Pi' = x@W1a + xn@W1b + b1 ; Pj = x@W1c + xn@W1d ----
__global__ __launch_bounds__(512) void k_proj(const float* __restrict__ x,
                                              const float* __restrict__ W1,
                                              const float* __restrict__ b1,
                                              float* __restrict__ PiP,
                                              float* __restrict__ Pj) {
  __shared__ float xs[9][128];            // rows n0..n0+8 (next wraps mod 256)
  const int b = blockIdx.x >> 5;
  const int n0 = (blockIdx.x & 31) * 8;
  const int tid = threadIdx.x;
  for (int it = 0; it < 3; ++it) {
    int e = it * 512 + tid;
    if (e < 1152) {
      int r = e >> 7, d = e & 127;
      int row = (n0 + r) & 255;
      xs[r][d] = x[(b * 256 + row) * 128 + d];
    }
  }
  __syncthreads();
  const int c = tid & 255;                // output channel 0..255
  const int rh = tid >> 8;                // 0/1 -> rows rh*4..rh*4+3
  float api[4] = {0, 0, 0, 0}, apj[4] = {0, 0, 0, 0};
  const float* W1c_ = W1 + c;
  for (int d = 0; d < 128; ++d) {
    float wa = W1c_[d * 256];
    float wb = W1c_[(128 + d) * 256];
    float wc = W1c_[(256 + d) * 256];
    float wd = W1c_[(384 + d) * 256];
    float x0 = xs[rh * 4 + 0][d], x1 = xs[rh * 4 + 1][d], x2 = xs[rh * 4 + 2][d];
    float x3 = xs[rh * 4 + 3][d], x4 = xs[rh * 4 + 4][d];
    api[0] += x0 * wa + x1 * wb;  apj[0] += x0 * wc + x1 * wd;
    api[1] += x1 * wa + x2 * wb;  apj[1] += x1 * wc + x2 * wd;
    api[2] += x2 * wa + x3 * wb;  apj[2] += x2 * wc + x3 * wd;
    api[3] += x3 * wa + x4 * wb;  apj[3] += x3 * wc + x4 * wd;
  }
  const float bv = b1[c];
  for (int r = 0; r < 4; ++r) {
    int n = n0 + rh * 4 + r;
    PiP[(b * 256 + n) * 256 + c] = api[r] + bv;  // b1 folded into Pi'
    Pj[(b * 256 + n) * 256 + c] = apj[r];
  }
}

// ---------------- main: per (b, i, j-tile): [128x256]@[256x128] MFMA GEMM --
// A[jl][c] = relu(Pi'[i][c] + Pj[j][c]) generated in LDS (bf16, XOR-swizzled
// 16B blocks so rows need no padding: 2x 32KB = exactly 64KB LDS, 2 blk/CU).
__global__ __launch_bounds__(256) void k_main(
    const float* __restrict__ PiP, const float* __restrict__ Pj,
    const unsigned short* __restrict__ W2T, const float* __restrict__ b2,
    const float* __restrict__ W3, const float* __restrict__ b3,
    float* __restrict__ outm) {
  const int bid = blockIdx.x;
  const int jt = bid & 1;            // j-tile (0: j<128, 1: j>=128)
  const int i = (bid >> 1) & 255;
  const int b = bid >> 9;
  if (i >= jt * 128 + 126) return;   // whole tile fails j >= i+2 (pre-zeroed)

  __shared__ unsigned short W2s[128][128];  // [n][k'] swizzled, 32KB
  __shared__ unsigned short As[128][128];   // [jl][c'] swizzled, 32KB

  const int tid = threadIdx.x;
  const int wv = tid >> 6, lane = tid & 63, quad = lane >> 4, l15 = lane & 15;

  floatx4 acc[2][8];
#pragma unroll
  for (int mt = 0; mt < 2; ++mt)
#pragma unroll
    for (int nt = 0; nt < 8; ++nt) acc[mt][nt] = (floatx4)0.f;

  const float* PiRow = PiP + (b * 256 + i) * 256;
  const float* Pjb = Pj + (b * 256 + jt * 128) * 256;

  for (int kc = 0; kc < 2; ++kc) {   // K=256 in two 128 chunks
    if (kc) __syncthreads();
    // stage W2 chunk (bf16, 16B-block XOR swizzle on (k-block ^ n&15))
#pragma unroll
    for (int it = 0; it < 8; ++it) {
      int e = it * 256 + tid;
      int n = e >> 4, v = e & 15;
      int col = ((v ^ (n & 15)) << 3);
      *(uint4*)&W2s[n][col] = *(const uint4*)(W2T + n * 256 + kc * 128 + v * 8);
    }
    // generate A chunk: relu(Pi'[i] + Pj[j]) -> bf16
#pragma unroll
    for (int it = 0; it < 16; ++it) {
      int e = it * 256 + tid;
      int jl = e >> 5, c4 = e & 31;
      const float4 pj4 = *(const float4*)(Pjb + jl * 256 + kc * 128 + c4 * 4);
      const float4 pi4 = *(const float4*)(PiRow + kc * 128 + c4 * 4);
      ushort4 h;
      h.x = f2bf(fmaxf(pi4.x + pj4.x, 0.f));
      h.y = f2bf(fmaxf(pi4.y + pj4.y, 0.f));
      h.z = f2bf(fmaxf(pi4.z + pj4.z, 0.f));
      h.w = f2bf(fmaxf(pi4.w + pj4.w, 0.f));
      int bc = c4 >> 1, half = c4 & 1;
      int col = ((bc ^ (jl & 15)) << 3) + (half << 2);
      *(ushort4*)&As[jl][col] = h;
    }
    __syncthreads();
    // MFMA: wave wv computes rows [wv*32, wv*32+32) x all 128 cols
#pragma unroll
    for (int ks = 0; ks < 4; ++ks) {
      int bc = ks * 4 + quad;
      short8 af0 = *(const short8*)&As[wv * 32 + l15][(bc ^ l15) << 3];
      short8 af1 = *(const short8*)&As[wv * 32 + 16 + l15][(bc ^ l15) << 3];
#pragma unroll
      for (int nt = 0; nt < 8; ++nt) {
        short8 bfr = *(const short8*)&W2s[nt * 16 + l15][(bc ^ l15) << 3];
        acc[0][nt] = __builtin_amdgcn_mfma_f32_16x16x32_bf16(af0, bfr, acc[0][nt], 0, 0, 0);
        acc[1][nt] = __builtin_amdgcn_mfma_f32_16x16x32_bf16(af1, bfr, acc[1][nt], 0, 0, 0);
      }
    }
  }

  // epilogue: score[j] = tanh(sum_k W3[k]*relu(C[j,k]+b2[k]) + b3), masked
  const float b3v = b3[0];
  float w3v[8], b2v[8];
#pragma unroll
  for (int nt = 0; nt < 8; ++nt) {
    w3v[nt] = W3[nt * 16 + l15];
    b2v[nt] = b2[nt * 16 + l15];
  }
#pragma unroll
  for (int mt = 0; mt < 2; ++mt) {
    float p0 = 0, p1 = 0, p2 = 0, p3 = 0;
#pragma unroll
    for (int nt = 0; nt < 8; ++nt) {
      floatx4 a = acc[mt][nt];
      p0 += fmaxf(a[0] + b2v[nt], 0.f) * w3v[nt];
      p1 += fmaxf(a[1] + b2v[nt], 0.f) * w3v[nt];
      p2 += fmaxf(a[2] + b2v[nt], 0.f) * w3v[nt];
      p3 += fmaxf(a[3] + b2v[nt], 0.f) * w3v[nt];
    }
#pragma unroll
    for (int m = 8; m >= 1; m >>= 1) {   // reduce over 16 cols held per quad
      p0 += __shfl_xor(p0, m, 16);
      p1 += __shfl_xor(p1, m, 16);
      p2 += __shfl_xor(p2, m, 16);
      p3 += __shfl_xor(p3, m, 16);
    }
    if (l15 == 0) {
      const int jbase = jt * 128 + wv * 32 + mt * 16 + quad * 4;
      float ps[4] = {p0, p1, p2, p3};
#pragma unroll
      for (int r = 0; r < 4; ++r) {
        int j = jbase + r;
        float s = tanhf(ps[r] + b3v);
        bool valid = (j >= i + 2) && (j - i != 255);
        outm[(b * 256 + i) * 256 + j] = valid ? s : 0.f;
      }
    }
  }
}

extern "C" void kernel_launch(void* const* d_in, const int* in_sizes, int n_in,
                              void* d_out, int out_size, void* d_ws, size_t ws_size,
                              hipStream_t stream) {
  const float* x  = (const float*)d_in[0];   // [8,256,128]
  const float* W1 = (const float*)d_in[1];   // [512,256]
  const float* b1 = (const float*)d_in[2];   // [256]
  const float* W2 = (const float*)d_in[3];   // [256,128]
  const float* b2 = (const float*)d_in[4];   // [128]
  const float* W3 = (const float*)d_in[5];   // [128]
  const float* b3 = (const float*)d_in[6];   // [1]
  float* out = (float*)d_out;

  // workspace: Pi' fp32 (2MB) | Pj fp32 (2MB) | W2T bf16 (64KB)
  float* PiP = (float*)d_ws;
  float* Pj  = PiP + 8 * 256 * 256;
  unsigned short* W2T = (unsigned short*)(Pj + 8 * 256 * 256);

  k_prep<<<2184, 256, 0, stream>>>(W2, out, W2T);          // 559104 elems
  k_proj<<<256, 512, 0, stream>>>(x, W1, b1, PiP, Pj);
  k_main<<<4096, 256, 0, stream>>>(PiP, Pj, W2T, b2, W3, b3, out + 2048);
}

// Round 2
// 131.666 us; speedup vs baseline: 1.1734x; 1.1734x over previous
//
#include <hip/hip_runtime.h>

// B=8, N=256, D=128, 2D=256.
// out = tour [8,256] (arange) ++ improvement_matrix [8,256,256].

typedef __attribute__((ext_vector_type(8))) short short8;
typedef __attribute__((ext_vector_type(4))) float floatx4;

static __device__ __forceinline__ unsigned short f2bf(float f) {
  unsigned int x = __float_as_uint(f);
  x += 0x7fff + ((x >> 16) & 1);   // RNE fp32 -> bf16
  return (unsigned short)(x >> 16);
}

// ---- k_proj: blocks 0..511 proj GEMM; 512..527 W2->bf16T; 528 tour out ----
// Pi' = x@W1a + x_next@W1b + b1 ; Pj = x@W1c + x_next@W1d  (both stored bf16)
__global__ __launch_bounds__(256) void k_proj(
    const float* __restrict__ x, const float* __restrict__ W1,
    const float* __restrict__ b1, const float* __restrict__ W2,
    float* __restrict__ out, unsigned short* __restrict__ PiB,
    unsigned short* __restrict__ PjB, unsigned short* __restrict__ W2T) {
  const int blk = blockIdx.x;
  const int tid = threadIdx.x;
  if (blk >= 512) {
    if (blk == 528) {
#pragma unroll
      for (int it = 0; it < 8; ++it) {
        int e = it * 256 + tid;
        out[e] = (float)(e & 255);          // improved_tour rows = arange
      }
    } else {
      int base = (blk - 512) * 2048;        // 16 blocks x 2048 = 32768 W2 elems
#pragma unroll
      for (int it = 0; it < 8; ++it) {
        int e = base + it * 256 + tid;      // W2 is [256 k][128 n]
        int k = e >> 7, n = e & 127;
        W2T[n * 256 + k] = f2bf(W2[e]);     // W2T[n][k]
      }
    }
    return;
  }
  __shared__ float xs[5][128];              // rows n0..n0+4 (wrap mod 256)
  const int b = blk >> 6;
  const int n0 = (blk & 63) * 4;
  for (int it = 0; it < 3; ++it) {
    int e = it * 256 + tid;
    if (e < 640) {
      int r = e >> 7, d = e & 127;
      xs[r][d] = x[(b * 256 + ((n0 + r) & 255)) * 128 + d];
    }
  }
  __syncthreads();
  const int c = tid;                        // output channel 0..255
  float api[4] = {0, 0, 0, 0}, apj[4] = {0, 0, 0, 0};
#pragma unroll 4
  for (int d = 0; d < 128; ++d) {
    float wa = W1[d * 256 + c];
    float wb = W1[(128 + d) * 256 + c];
    float wc = W1[(256 + d) * 256 + c];
    float wd = W1[(384 + d) * 256 + c];
    float xv[5];
#pragma unroll
    for (int r = 0; r < 5; ++r) xv[r] = xs[r][d];
#pragma unroll
    for (int r = 0; r < 4; ++r) {
      api[r] += xv[r] * wa + xv[r + 1] * wb;
      apj[r] += xv[r] * wc + xv[r + 1] * wd;
    }
  }
  const float bv = b1[c];
#pragma unroll
  for (int r = 0; r < 4; ++r) {
    int n = n0 + r;
    PiB[(b * 256 + n) * 256 + c] = f2bf(api[r] + bv);  // b1 folded into Pi'
    PjB[(b * 256 + n) * 256 + c] = f2bf(apj[r]);
  }
}

// ---- k_main: block = (b, i), all 256 j x 128 n. 4 waves x 64 j each. -------
// W2 (full K=256) in LDS once, ONE barrier. A-frags built in registers from
// bf16 Pi/Pj (global, L2-hot): relu(Pi+Pj) packed via v_perm truncation.
__global__ __launch_bounds__(256, 2) void k_main(
    const unsigned short* __restrict__ PiB, const unsigned short* __restrict__ PjB,
    const unsigned short* __restrict__ W2T, const float* __restrict__ b2,
    const float* __restrict__ W3, const float* __restrict__ b3,
    float* __restrict__ outm) {
  const int bid = blockIdx.x;          // 2048 = 8 b * 256 i
  const int i = bid & 255;
  const int b = bid >> 8;
  const int tid = threadIdx.x;
  const int wr = tid >> 6, lane = tid & 63, quad = lane >> 4, l15 = lane & 15;

  __shared__ unsigned short W2s[128][256];   // [n][k'] 16B-block XOR swizzle

  // stage full W2 (64KB): 4096 16B chunks, 16/thread, coalesced global reads
#pragma unroll
  for (int it = 0; it < 16; ++it) {
    int e = it * 256 + tid;
    int n = e >> 5, v = e & 31;                     // v = k-block 0..31
    int col = ((v & 16) | ((v ^ n) & 15)) << 3;
    *(uint4*)&W2s[n][col] = *(const uint4*)(W2T + n * 256 + v * 8);
  }
  __syncthreads();

  float* orow = outm + (b * 256 + i) * 256 + wr * 64;
  if (i > wr * 64 + 61) {              // whole wave's j-range invalid
    orow[lane] = 0.f;
    return;
  }

  floatx4 acc[4][8];
#pragma unroll
  for (int mt = 0; mt < 4; ++mt)
#pragma unroll
    for (int nt = 0; nt < 8; ++nt) acc[mt][nt] = (floatx4)0.f;

  const unsigned short* PiRow = PiB + (b * 256 + i) * 256 + quad * 8;
  const unsigned short* Pjb = PjB + (b * 256 + wr * 64 + l15) * 256 + quad * 8;

  for (int ks = 0; ks < 8; ++ks) {
    // Pi fragment for this k-chunk (shared across mt), unpack to fp32
    const uint4 pi4 = *(const uint4*)(PiRow + ks * 32);
    float pif[8];
#pragma unroll
    for (int p = 0; p < 4; ++p) {
      unsigned w = ((const unsigned*)&pi4)[p];
      pif[2 * p]     = __uint_as_float(w << 16);
      pif[2 * p + 1] = __uint_as_float(w & 0xffff0000u);
    }
    // build A-fragments in registers: relu(Pi + Pj[j]) -> packed bf16 (trunc)
    short8 af[4];
#pragma unroll
    for (int mt = 0; mt < 4; ++mt) {
      const uint4 pj4 = *(const uint4*)(Pjb + mt * 16 * 256 + ks * 32);
      union { unsigned u[4]; short8 s; } cvt;
#pragma unroll
      for (int p = 0; p < 4; ++p) {
        unsigned w = ((const unsigned*)&pj4)[p];
        float lo = fmaxf(pif[2 * p]     + __uint_as_float(w << 16), 0.f);
        float hi = fmaxf(pif[2 * p + 1] + __uint_as_float(w & 0xffff0000u), 0.f);
        cvt.u[p] = __builtin_amdgcn_perm(__float_as_uint(hi), __float_as_uint(lo),
                                         0x07060302u);  // {hi16(hi),hi16(lo)}
      }
      af[mt] = cvt.s;
    }
    // MFMA: 8 n-tiles x 4 m-tiles, B-frag read once per nt
    const int bk = ks * 4 + quad;
#pragma unroll
    for (int nt = 0; nt < 8; ++nt) {
      int n = nt * 16 + l15;
      int col = ((bk & 16) | ((bk ^ n) & 15)) << 3;
      short8 bfr = *(const short8*)&W2s[n][col];
      acc[0][nt] = __builtin_amdgcn_mfma_f32_16x16x32_bf16(af[0], bfr, acc[0][nt], 0, 0, 0);
      acc[1][nt] = __builtin_amdgcn_mfma_f32_16x16x32_bf16(af[1], bfr, acc[1][nt], 0, 0, 0);
      acc[2][nt] = __builtin_amdgcn_mfma_f32_16x16x32_bf16(af[2], bfr, acc[2][nt], 0, 0, 0);
      acc[3][nt] = __builtin_amdgcn_mfma_f32_16x16x32_bf16(af[3], bfr, acc[3][nt], 0, 0, 0);
    }
  }

  // epilogue: score[j] = tanh(sum_n W3[n]*relu(C[j,n]+b2[n]) + b3), masked
  const float b3v = b3[0];
  float w3v[8], b2v[8];
#pragma unroll
  for (int nt = 0; nt < 8; ++nt) {
    w3v[nt] = W3[nt * 16 + l15];
    b2v[nt] = b2[nt * 16 + l15];
  }
#pragma unroll
  for (int mt = 0; mt < 4; ++mt) {
    float p0 = 0, p1 = 0, p2 = 0, p3 = 0;
#pragma unroll
    for (int nt = 0; nt < 8; ++nt) {
      floatx4 a = acc[mt][nt];
      p0 += fmaxf(a[0] + b2v[nt], 0.f) * w3v[nt];
      p1 += fmaxf(a[1] + b2v[nt], 0.f) * w3v[nt];
      p2 += fmaxf(a[2] + b2v[nt], 0.f) * w3v[nt];
      p3 += fmaxf(a[3] + b2v[nt], 0.f) * w3v[nt];
    }
#pragma unroll
    for (int m = 8; m >= 1; m >>= 1) {   // reduce over the 16 n-cols per quad
      p0 += __shfl_xor(p0, m, 16);
      p1 += __shfl_xor(p1, m, 16);
      p2 += __shfl_xor(p2, m, 16);
      p3 += __shfl_xor(p3, m, 16);
    }
    if (l15 == 0) {
      const int jl = wr * 64 + mt * 16 + quad * 4;   // global j of reg 0
      float ps[4] = {p0, p1, p2, p3};
#pragma unroll
      for (int r = 0; r < 4; ++r) {
        int j = jl + r;
        float s = tanhf(ps[r] + b3v);
        bool valid = (j >= i + 2) && (j - i != 255);
        orow[mt * 16 + quad * 4 + r] = valid ? s : 0.f;
      }
    }
  }
}

extern "C" void kernel_launch(void* const* d_in, const int* in_sizes, int n_in,
                              void* d_out, int out_size, void* d_ws, size_t ws_size,
                              hipStream_t stream) {
  const float* x  = (const float*)d_in[0];   // [8,256,128]
  const float* W1 = (const float*)d_in[1];   // [512,256]
  const float* b1 = (const float*)d_in[2];   // [256]
  const float* W2 = (const float*)d_in[3];   // [256,128]
  const float* b2 = (const float*)d_in[4];   // [128]
  const float* W3 = (const float*)d_in[5];   // [128]
  const float* b3 = (const float*)d_in[6];   // [1]
  float* out = (float*)d_out;

  // workspace: PiB bf16 (1MB) | PjB bf16 (1MB) | W2T bf16 (64KB)
  unsigned short* PiB = (unsigned short*)d_ws;
  unsigned short* PjB = PiB + 8 * 256 * 256;
  unsigned short* W2T = PjB + 8 * 256 * 256;

  k_proj<<<529, 256, 0, stream>>>(x, W1, b1, W2, out, PiB, PjB, W2T);
  k_main<<<2048, 256, 0, stream>>>(PiB, PjB, W2T, b2, W3, b3, out + 2048);
}